// Round 4
// baseline (162.145 us; speedup 1.0000x reference)
//
#include <hip/hip_runtime.h>

#define BB 4
#define TT 256
#define LL 128
#define EE 64
#define SCALE 0.125f  // 1/sqrt(64)

// Kernel A: one block per (b,l). dot[t] = <note[b,t,:], harm[b,l,:]>, global max
// M_bl of raw = dot*SCALE, then fp64 inclusive prefix sums of ex = exp(raw-M)
// and ex*dot. Wave shfl scan + one LDS round for inter-wave offsets.
// P[b][t][l] = double2(Sd, Sn).
__global__ __launch_bounds__(256) void k_prefix(const float* __restrict__ note,
                                                const float* __restrict__ harm,
                                                double2* __restrict__ P) {
    int b = blockIdx.x >> 7;     // L=128 blocks per b
    int l = blockIdx.x & 127;
    int t = threadIdx.x;         // 256 threads = t
    int lane = t & 63;
    int wave = t >> 6;

    __shared__ __align__(16) float h[EE];
    if (t < EE) h[t] = harm[(b * LL + l) * EE + t];
    __syncthreads();

    const float4* n4 = (const float4*)(note + (b * TT + t) * EE);
    const float4* h4 = (const float4*)h;
    float acc = 0.f;
#pragma unroll
    for (int i = 0; i < EE / 4; ++i) {
        float4 nv = n4[i];
        float4 hv = h4[i];
        acc += nv.x * hv.x + nv.y * hv.y + nv.z * hv.z + nv.w * hv.w;
    }
    float dot = acc;
    float raw = dot * SCALE;

    // block max-reduce
    float m = raw;
#pragma unroll
    for (int off = 32; off > 0; off >>= 1) m = fmaxf(m, __shfl_xor(m, off));
    __shared__ float wmax[4];
    if (lane == 0) wmax[wave] = m;
    __syncthreads();
    float M = fmaxf(fmaxf(wmax[0], wmax[1]), fmaxf(wmax[2], wmax[3]));

    float ex = __expf(raw - M);
    double vd = (double)ex;
    double vn = (double)ex * (double)dot;

    // intra-wave inclusive scan (fp64) via shfl_up
#pragma unroll
    for (int off = 1; off < 64; off <<= 1) {
        double od = __shfl_up(vd, off);
        double on = __shfl_up(vn, off);
        if (lane >= off) { vd += od; vn += on; }
    }
    __shared__ double wtd[4], wtn[4];
    if (lane == 63) { wtd[wave] = vd; wtn[wave] = vn; }
    __syncthreads();
    double od = 0.0, on = 0.0;
#pragma unroll
    for (int w = 0; w < 3; ++w) {
        if (w < wave) { od += wtd[w]; on += wtn[w]; }
    }
    vd += od;
    vn += on;

    P[(b * TT + t) * LL + l] = make_double2(vd, vn);
}

// Kernel B (fused zero-fill + valid, plain cacheable stores):
//   blocks [0, 512):    balanced zero-fill. Pair-block p handles rows s=p and
//                       s=255-p of batch b -> uniform 255*512B per block,
//                       each row prefix a contiguous memset-grade run.
//   blocks [512, 1152): valid-region blocks, compacted grid — only (st,eq)
//                       pairs with e_base+63 >= s0. Per-b counts by eq:
//                       16,32,48,64 -> r-ranges [0,16) [16,48) [48,96) [96,160).
//                       Boundary blocks SKIP e<s stores (zero path owns them).
__global__ __launch_bounds__(256) void k_out3(const double2* __restrict__ P,
                                              float* __restrict__ out) {
    int blk = blockIdx.x;
    const int srow = TT * LL;     // floats between s rows

    if (blk < 512) {
        // -------- balanced zero-fill path --------
        int b = blk >> 7;
        int p = blk & 127;
        float4 z = make_float4(0.f, 0.f, 0.f, 0.f);

        float* base1 = out + ((size_t)(b * TT + p) * TT) * LL;
        int n1 = p * (LL / 4);            // float4 count, row s=p
        for (int i = threadIdx.x; i < n1; i += 256)
            *(float4*)(base1 + 4 * i) = z;

        int s2 = 255 - p;
        float* base2 = out + ((size_t)(b * TT + s2) * TT) * LL;
        int n2 = s2 * (LL / 4);           // float4 count, row s=255-p
        for (int i = threadIdx.x; i < n2; i += 256)
            *(float4*)(base2 + 4 * i) = z;
        return;
    }

    // -------- valid-region path --------
    // decode blk-512 -> (b, st, eq): 160 (st,eq) pairs per b
    int vblk = blk - 512;
    int b = vblk / 160;
    int r = vblk - b * 160;
    int eq, st;
    if (r < 16)      { eq = 0; st = r; }
    else if (r < 48) { eq = 1; st = r - 16; }
    else if (r < 96) { eq = 2; st = r - 48; }
    else             { eq = 3; st = r - 96; }

    int lq = threadIdx.x & 31;
    int eo = threadIdx.x >> 5;    // [0,8)
    int s0 = st * 4;
    int l0 = lq * 4;
    int e_base = eq * 64;

    // Ps[k][j] = P[b][s0+k-1][l0+j] (0 if s==0)
    double Psx[4][4], Psy[4][4];
#pragma unroll
    for (int k = 0; k < 4; ++k) {
        int s = s0 + k;
        if (s > 0) {
            const double2* ps = P + (b * TT + s - 1) * LL + l0;
#pragma unroll
            for (int j = 0; j < 4; ++j) {
                double2 v = ps[j];
                Psx[k][j] = v.x;
                Psy[k][j] = v.y;
            }
        } else {
#pragma unroll
            for (int j = 0; j < 4; ++j) { Psx[k][j] = 0.0; Psy[k][j] = 0.0; }
        }
    }

    const double2* pbase = P + b * TT * LL + l0;
    float* obase = out + ((size_t)(b * TT + s0) * TT) * LL + l0;

    if (e_base >= s0 + 3) {
        // fully valid block: no predication
#pragma unroll 4
        for (int it = 0; it < 8; ++it) {
            int e = e_base + it * 8 + eo;
            const double2* pe = pbase + e * LL;
            double2 Pe[4];
#pragma unroll
            for (int j = 0; j < 4; ++j) Pe[j] = pe[j];

#pragma unroll
            for (int k = 0; k < 4; ++k) {
                float4 rv;
                float* rp = (float*)&rv;
#pragma unroll
                for (int j = 0; j < 4; ++j) {
                    float den = (float)(Pe[j].x - Psx[k][j]);
                    float num = (float)(Pe[j].y - Psy[k][j]);
                    rp[j] = __fdividef(num, fmaxf(den, 1e-30f));
                }
                *(float4*)(obase + k * srow + e * LL) = rv;
            }
        }
        return;
    }

    // boundary block: skip e<s stores entirely (zero path owns them)
#pragma unroll 2
    for (int it = 0; it < 8; ++it) {
        int e = e_base + it * 8 + eo;
        const double2* pe = pbase + e * LL;
        double2 Pe[4];
#pragma unroll
        for (int j = 0; j < 4; ++j) Pe[j] = pe[j];

#pragma unroll
        for (int k = 0; k < 4; ++k) {
            if (e >= s0 + k) {
                float4 rv;
                float* rp = (float*)&rv;
#pragma unroll
                for (int j = 0; j < 4; ++j) {
                    float den = (float)(Pe[j].x - Psx[k][j]);
                    float num = (float)(Pe[j].y - Psy[k][j]);
                    rp[j] = __fdividef(num, fmaxf(den, 1e-30f));
                }
                *(float4*)(obase + k * srow + e * LL) = rv;
            }
        }
    }
}

extern "C" void kernel_launch(void* const* d_in, const int* in_sizes, int n_in,
                              void* d_out, int out_size, void* d_ws, size_t ws_size,
                              hipStream_t stream) {
    const float* note = (const float*)d_in[0];   // [B,T,E]
    const float* harm = (const float*)d_in[1];   // [B,L,E]
    float* out = (float*)d_out;                  // [B,T,T,L]

    double2* P = (double2*)d_ws;                 // [B,T,L] double2 = 2 MB

    k_prefix<<<BB * LL, 256, 0, stream>>>(note, harm, P);
    k_out3<<<512 + 640, 256, 0, stream>>>(P, out);
}

// Round 6
// 161.240 us; speedup vs baseline: 1.0056x; 1.0056x over previous
//
#include <hip/hip_runtime.h>

#define BB 4
#define TT 256
#define LL 128
#define EE 64
#define SCALE 0.125f  // 1/sqrt(64)

// Kernel A: one block per (b,l). dot[t] = <note[b,t,:], harm[b,l,:]>, global max
// M_bl of raw = dot*SCALE, then fp64 inclusive prefix sums of ex = exp(raw-M)
// and ex*dot. Wave shfl scan + one LDS round for inter-wave offsets.
// P[b][t][l] = double2(Sd, Sn).
__global__ __launch_bounds__(256) void k_prefix(const float* __restrict__ note,
                                                const float* __restrict__ harm,
                                                double2* __restrict__ P) {
    int b = blockIdx.x >> 7;     // L=128 blocks per b
    int l = blockIdx.x & 127;
    int t = threadIdx.x;         // 256 threads = t
    int lane = t & 63;
    int wave = t >> 6;

    __shared__ __align__(16) float h[EE];
    if (t < EE) h[t] = harm[(b * LL + l) * EE + t];
    __syncthreads();

    const float4* n4 = (const float4*)(note + (b * TT + t) * EE);
    const float4* h4 = (const float4*)h;
    float acc = 0.f;
#pragma unroll
    for (int i = 0; i < EE / 4; ++i) {
        float4 nv = n4[i];
        float4 hv = h4[i];
        acc += nv.x * hv.x + nv.y * hv.y + nv.z * hv.z + nv.w * hv.w;
    }
    float dot = acc;
    float raw = dot * SCALE;

    // block max-reduce
    float m = raw;
#pragma unroll
    for (int off = 32; off > 0; off >>= 1) m = fmaxf(m, __shfl_xor(m, off));
    __shared__ float wmax[4];
    if (lane == 0) wmax[wave] = m;
    __syncthreads();
    float M = fmaxf(fmaxf(wmax[0], wmax[1]), fmaxf(wmax[2], wmax[3]));

    float ex = __expf(raw - M);
    double vd = (double)ex;
    double vn = (double)ex * (double)dot;

    // intra-wave inclusive scan (fp64) via shfl_up
#pragma unroll
    for (int off = 1; off < 64; off <<= 1) {
        double od = __shfl_up(vd, off);
        double on = __shfl_up(vn, off);
        if (lane >= off) { vd += od; vn += on; }
    }
    __shared__ double wtd[4], wtn[4];
    if (lane == 63) { wtd[wave] = vd; wtn[wave] = vn; }
    __syncthreads();
    double od = 0.0, on = 0.0;
#pragma unroll
    for (int w = 0; w < 3; ++w) {
        if (w < wave) { od += wtd[w]; on += wtn[w]; }
    }
    vd += od;
    vn += on;

    P[(b * TT + t) * LL + l] = make_double2(vd, vn);
}

// Kernel B: memset-isomorphic output writer.
// One block per (b,s) row: a single 128 KB CONTIGUOUS ascending store stream
// (same shape as the 6.5 TB/s fillBufferAligned kernel). Thread tid owns the
// fixed l-quad l0=(tid&31)*4 (Ps in 4 registers, loaded once) and walks
// e = (tid>>5) + 8k, k=0..31. Zeros (e<s) and computed values (e>=s) are
// emitted in the same linear sweep — one writer per row, perfect balance
// (every block stores exactly 128 KB). Divergence only at the e==s line.
__global__ __launch_bounds__(256) void k_out4(const double2* __restrict__ P,
                                              float* __restrict__ out) {
    int b = blockIdx.x >> 8;      // 256 s-rows per b
    int s = blockIdx.x & 255;
    int tid = threadIdx.x;
    int lq = tid & 31;
    int l0 = lq * 4;
    int e0 = tid >> 5;            // [0,8)

    // Ps[j] = P[b][s-1][l0+j] (0 if s==0) — fixed per thread
    double Psx[4], Psy[4];
    if (s > 0) {
        const double2* ps = P + ((size_t)(b * TT + s - 1)) * LL + l0;
#pragma unroll
        for (int j = 0; j < 4; ++j) {
            double2 v = ps[j];
            Psx[j] = v.x;
            Psy[j] = v.y;
        }
    } else {
#pragma unroll
        for (int j = 0; j < 4; ++j) { Psx[j] = 0.0; Psy[j] = 0.0; }
    }

    const double2* pb = P + (size_t)b * TT * LL + l0;
    float* rowbase = out + ((size_t)(b * TT + s)) * TT * LL;
    const float4 z = make_float4(0.f, 0.f, 0.f, 0.f);

#pragma unroll 4
    for (int k = 0; k < 32; ++k) {
        int e = e0 + 8 * k;
        float* dst = rowbase + ((e * 32 + lq) << 2);   // = rowbase + e*LL + l0
        if (e < s) {
            *(float4*)dst = z;
        } else {
            const double2* pe = pb + (size_t)e * LL;
            double2 Pe0 = pe[0], Pe1 = pe[1], Pe2 = pe[2], Pe3 = pe[3];
            float4 rv;
            rv.x = __fdividef((float)(Pe0.y - Psy[0]),
                              fmaxf((float)(Pe0.x - Psx[0]), 1e-30f));
            rv.y = __fdividef((float)(Pe1.y - Psy[1]),
                              fmaxf((float)(Pe1.x - Psx[1]), 1e-30f));
            rv.z = __fdividef((float)(Pe2.y - Psy[2]),
                              fmaxf((float)(Pe2.x - Psx[2]), 1e-30f));
            rv.w = __fdividef((float)(Pe3.y - Psy[3]),
                              fmaxf((float)(Pe3.x - Psx[3]), 1e-30f));
            *(float4*)dst = rv;
        }
    }
}

extern "C" void kernel_launch(void* const* d_in, const int* in_sizes, int n_in,
                              void* d_out, int out_size, void* d_ws, size_t ws_size,
                              hipStream_t stream) {
    const float* note = (const float*)d_in[0];   // [B,T,E]
    const float* harm = (const float*)d_in[1];   // [B,L,E]
    float* out = (float*)d_out;                  // [B,T,T,L]

    double2* P = (double2*)d_ws;                 // [B,T,L] double2 = 2 MB

    k_prefix<<<BB * LL, 256, 0, stream>>>(note, harm, P);
    k_out4<<<BB * TT, 256, 0, stream>>>(P, out);
}

// Round 7
// 149.592 us; speedup vs baseline: 1.0839x; 1.0779x over previous
//
#include <hip/hip_runtime.h>

#define BB 4
#define TT 256
#define LL 128
#define EE 64
#define SCALE 0.125f  // 1/sqrt(64)

// Kernel A: one block per (b,l). dot[t] = <note[b,t,:], harm[b,l,:]>, global max
// M_bl of raw = dot*SCALE, then fp64 inclusive prefix sums of ex = exp(raw-M)
// and ex*dot. Wave shfl scan + one LDS round for inter-wave offsets.
// P[b][t][l] = double2(Sd, Sn).
__global__ __launch_bounds__(256) void k_prefix(const float* __restrict__ note,
                                                const float* __restrict__ harm,
                                                double2* __restrict__ P) {
    int b = blockIdx.x >> 7;     // L=128 blocks per b
    int l = blockIdx.x & 127;
    int t = threadIdx.x;         // 256 threads = t
    int lane = t & 63;
    int wave = t >> 6;

    __shared__ __align__(16) float h[EE];
    if (t < EE) h[t] = harm[(b * LL + l) * EE + t];
    __syncthreads();

    const float4* n4 = (const float4*)(note + (b * TT + t) * EE);
    const float4* h4 = (const float4*)h;
    float acc = 0.f;
#pragma unroll
    for (int i = 0; i < EE / 4; ++i) {
        float4 nv = n4[i];
        float4 hv = h4[i];
        acc += nv.x * hv.x + nv.y * hv.y + nv.z * hv.z + nv.w * hv.w;
    }
    float dot = acc;
    float raw = dot * SCALE;

    // block max-reduce
    float m = raw;
#pragma unroll
    for (int off = 32; off > 0; off >>= 1) m = fmaxf(m, __shfl_xor(m, off));
    __shared__ float wmax[4];
    if (lane == 0) wmax[wave] = m;
    __syncthreads();
    float M = fmaxf(fmaxf(wmax[0], wmax[1]), fmaxf(wmax[2], wmax[3]));

    float ex = __expf(raw - M);
    double vd = (double)ex;
    double vn = (double)ex * (double)dot;

    // intra-wave inclusive scan (fp64) via shfl_up
#pragma unroll
    for (int off = 1; off < 64; off <<= 1) {
        double od = __shfl_up(vd, off);
        double on = __shfl_up(vn, off);
        if (lane >= off) { vd += od; vn += on; }
    }
    __shared__ double wtd[4], wtn[4];
    if (lane == 63) { wtd[wave] = vd; wtn[wave] = vn; }
    __syncthreads();
    double od = 0.0, on = 0.0;
#pragma unroll
    for (int w = 0; w < 3; ++w) {
        if (w < wave) { od += wtd[w]; on += wtn[w]; }
    }
    vd += od;
    vn += on;

    P[(b * TT + t) * LL + l] = make_double2(vd, vn);
}

// Kernel B (k_out5): R0's proven tiling (s-tile of 4, Pe reused across the 4
// s-values -> 1:1 load:store bytes) with the occupancy/MLP fix:
//   - Ps (4 s x 4 l fp64 pairs, was 64 VGPRs) staged in LDS, 80 B-padded rows
//     (lane stride 20 dwords, gcd(20,32)=4 -> only 4-way bank aliasing).
//   - __launch_bounds__(256, 8): VGPR <= 64 -> 8 blocks/CU -> 32 waves/CU.
//   - e-range 32 -> 2048 blocks = exactly 8/CU, full-device residency.
// Little's law: 2x waves/CU -> 2x outstanding L2 loads -> k_out goes from
// load-latency-limited (~3.5 TB/s) toward store-limited (~6.5 TB/s).
#define KSTRIDE 2560   // bytes per s-row in LDS: 32 lanes * 80
__global__ __launch_bounds__(256, 8) void k_out5(const double2* __restrict__ P,
                                                 float* __restrict__ out) {
    int blk = blockIdx.x;
    int eh = blk & 7;             // e_base = eh*32
    int st = (blk >> 3) & 63;     // s0 = st*4
    int b  = blk >> 9;

    int tid = threadIdx.x;
    int lq = tid & 31;
    int eo = tid >> 5;            // [0,8)
    int s0 = st * 4;
    int l0 = lq * 4;
    int e_base = eh * 32;
    const int srow = TT * LL;     // floats between s rows

    // stage Ps[k][l] = P[b][s0+k-1][l] (0 if s==0) into padded LDS
    __shared__ __align__(16) unsigned char ps_raw[4 * KSTRIDE];  // 10 KB
#pragma unroll
    for (int n = tid; n < 512; n += 256) {
        int k = n >> 7;           // [0,4)
        int l = n & 127;
        double2 v = make_double2(0.0, 0.0);
        int s = s0 + k;
        if (s > 0) v = P[((size_t)(b * TT + s - 1)) * LL + l];
        *(double2*)(ps_raw + k * KSTRIDE + (l >> 2) * 80 + (l & 3) * 16) = v;
    }
    __syncthreads();

    const double2* pbase = P + (size_t)b * TT * LL + l0;
    float* obase = out + ((size_t)(b * TT + s0)) * TT * LL + l0;
    const unsigned char* psbase = ps_raw + lq * 80;

#pragma unroll
    for (int it = 0; it < 4; ++it) {
        int e = e_base + it * 8 + eo;
        const double2* pe = pbase + e * LL;
        double2 Pe0 = pe[0], Pe1 = pe[1], Pe2 = pe[2], Pe3 = pe[3];

#pragma unroll
        for (int k = 0; k < 4; ++k) {
            const double2* psk = (const double2*)(psbase + k * KSTRIDE);
            double2 Ps0 = psk[0], Ps1 = psk[1], Ps2 = psk[2], Ps3 = psk[3];
            float4 rv;
            if (e >= s0 + k) {
                rv.x = __fdividef((float)(Pe0.y - Ps0.y),
                                  fmaxf((float)(Pe0.x - Ps0.x), 1e-30f));
                rv.y = __fdividef((float)(Pe1.y - Ps1.y),
                                  fmaxf((float)(Pe1.x - Ps1.x), 1e-30f));
                rv.z = __fdividef((float)(Pe2.y - Ps2.y),
                                  fmaxf((float)(Pe2.x - Ps2.x), 1e-30f));
                rv.w = __fdividef((float)(Pe3.y - Ps3.y),
                                  fmaxf((float)(Pe3.x - Ps3.x), 1e-30f));
            } else {
                rv = make_float4(0.f, 0.f, 0.f, 0.f);
            }
            *(float4*)(obase + k * srow + e * LL) = rv;
        }
    }
}

extern "C" void kernel_launch(void* const* d_in, const int* in_sizes, int n_in,
                              void* d_out, int out_size, void* d_ws, size_t ws_size,
                              hipStream_t stream) {
    const float* note = (const float*)d_in[0];   // [B,T,E]
    const float* harm = (const float*)d_in[1];   // [B,L,E]
    float* out = (float*)d_out;                  // [B,T,T,L]

    double2* P = (double2*)d_ws;                 // [B,T,L] double2 = 2 MB

    k_prefix<<<BB * LL, 256, 0, stream>>>(note, harm, P);
    k_out5<<<BB * 64 * 8, 256, 0, stream>>>(P, out);
}